// Round 12
// baseline (273.672 us; speedup 1.0000x reference)
//
#include <hip/hip_runtime.h>
#include <hip/hip_bf16.h>
#include <cstdint>
#include <cstddef>

// GATv2Conv forward, N=100000, E=1.6M, IN=128, H=4, C=32 (H*C=128).
//
// Pipeline — deterministic CSR build with ZERO global atomics (measured: 1.6M
// device-scope atomics cost >100 µs on MI355X; LDS atomics are ~free).
// Measured lessons: (r8) exact-fill persistent grids drain badly on irregular
// work; (r5-r10) agg sweet spot is stride-8 / 2-gathers-in-flight at high
// occupancy; (r10) padded gathers must be clamped to row 0 (L1-hot);
// (r11) with pads clamped, agg is VALU-issue-bound (VALUBusy 82%) -> this
// round vectorizes the hot loop as f32x2 so the compiler emits packed
// dual-FP32 VOP3P ops (v_pk_add_f32 / v_pk_mul_f32 / v_pk_fma_f32).
//   1) histW_k  : 8 ranges x 32 chunks, 1024-thr blocks; LDS u32 histogram of
//                 dst within range -> g[c][d] as u16. int4-vectorized edge
//                 reads. +1 block: W -> bf16 Wt.
//   2) mfma_gemm_k : xl = x@W_l, xr = x@W_r via v_mfma_f32_16x16x32_bf16.
//   3) scanA(fused colsum)/B -> scanCb_k (merged scanC+cbase).
//   4) scat_k   : LDS cursors seeded from base, LDS atomicAdd, direct store.
//                 blockIdx&7 == range -> XCD affinity. int4-vectorized.
//   5) agg_k    : one wave per dst node; 16 lanes/edge (8 ch each), 8 edges/
//                 iter in two 4-edge groups, both gathers + src loads issued
//                 up front; padded gather indices clamped to 0; packed-f32
//                 arithmetic. att pre-scaled by log2(e) -> one v_exp_f32.

#define NEG_SLOPE 0.2f
#define EPS_F 1e-16f
#define NRANGE 8
#define NCHUNK 32
#define SORT_B 1024
#define MAX_RSZ 12512   // >= ceil(N/NRANGE); LDS = 50 KB (u32)

typedef __attribute__((ext_vector_type(8))) short bf16x8;
typedef __attribute__((ext_vector_type(4))) float f32x4;
typedef __attribute__((ext_vector_type(2))) float f32x2;

static __device__ __forceinline__ unsigned f2bf(float f) {
    unsigned u = __float_as_uint(f);
    return (u + 0x7fffu + ((u >> 16) & 1u)) >> 16;   // RNE
}
static __device__ __forceinline__ float bf2f(unsigned h) {
    return __uint_as_float(h << 16);
}
static __device__ __forceinline__ float bflo(unsigned u) {
    return __uint_as_float(u << 16);                 // low bf16 of a u32 pair
}
static __device__ __forceinline__ float bfhi(unsigned u) {
    return __uint_as_float(u & 0xffff0000u);         // high bf16 of a u32 pair
}

// ------------- LDS-histogram pass + W transpose -------------
__global__ __launch_bounds__(SORT_B) void histW_k(const int* __restrict__ dst, int E, int N,
                                                  int rsz, int chunk_e,
                                                  unsigned short* __restrict__ g,
                                                  const float* __restrict__ Wl,
                                                  const float* __restrict__ Wr,
                                                  unsigned short* __restrict__ Wtl,
                                                  unsigned short* __restrict__ Wtr) {
    if (blockIdx.x == NRANGE * NCHUNK) {
        for (int mat = 0; mat < 2; ++mat) {
            const float* W = mat ? Wr : Wl;
            unsigned short* Wt = mat ? Wtr : Wtl;
            for (int i = 0; i < 16; ++i) {
                int idx = (int)threadIdx.x + i * SORT_B;
                int k = idx >> 7, n = idx & 127;
                Wt[n * 128 + k] = (unsigned short)f2bf(W[idx]);
            }
        }
        return;
    }
    __shared__ unsigned lcnt[MAX_RSZ];
    const int r = blockIdx.x & (NRANGE - 1);
    const int c = blockIdx.x >> 3;
    const unsigned r_lo = (unsigned)(r * rsz);
    const int e0 = c * chunk_e;
    const int e1 = min(e0 + chunk_e, E);

    for (int i = threadIdx.x; i < rsz; i += SORT_B) lcnt[i] = 0u;
    __syncthreads();

    int e_vec_end = e0;
    if ((((uintptr_t)(dst + e0)) & 15) == 0) {          // int4-aligned fast path
        const int nq = (e1 - e0) >> 2;
        const int4* dq = (const int4*)(dst + e0);
        for (int q = (int)threadIdx.x; q < nq; q += SORT_B) {
            int4 d4 = dq[q];
            unsigned dd;
            dd = (unsigned)d4.x - r_lo; if (dd < (unsigned)rsz) atomicAdd(&lcnt[dd], 1u);
            dd = (unsigned)d4.y - r_lo; if (dd < (unsigned)rsz) atomicAdd(&lcnt[dd], 1u);
            dd = (unsigned)d4.z - r_lo; if (dd < (unsigned)rsz) atomicAdd(&lcnt[dd], 1u);
            dd = (unsigned)d4.w - r_lo; if (dd < (unsigned)rsz) atomicAdd(&lcnt[dd], 1u);
        }
        e_vec_end = e0 + (nq << 2);
    }
    for (int e = e_vec_end + (int)threadIdx.x; e < e1; e += SORT_B) {
        unsigned dd = (unsigned)dst[e] - r_lo;
        if (dd < (unsigned)rsz) atomicAdd(&lcnt[dd], 1u);   // LDS atomic
    }
    __syncthreads();
    unsigned short* gc = g + (size_t)c * N + r_lo;
    int lim = min(rsz, N - (int)r_lo);
    for (int i = threadIdx.x; i < lim; i += SORT_B) gc[i] = (unsigned short)lcnt[i];
}

// ------------- MFMA GEMM: xl = x@Wl, xr = x@Wr (bf16 in, bf16 out) -------------
#define LROW 136
__global__ __launch_bounds__(256) void mfma_gemm_k(const float* __restrict__ A,
                                                   const unsigned short* __restrict__ Wtl,
                                                   const unsigned short* __restrict__ Wtr,
                                                   unsigned short* __restrict__ xl,
                                                   unsigned short* __restrict__ xr,
                                                   int nrows) {
    __shared__ unsigned short As[64 * LROW];
    __shared__ unsigned short Ws[128 * LROW];
    const int tid = threadIdx.x;
    const int wave = tid >> 6, lane = tid & 63;
    const int quad = lane >> 4, m16 = lane & 15;
    const int row0 = blockIdx.x * 64;

#pragma unroll
    for (int i = 0; i < 8; ++i) {
        int idx = tid + i * 256;
        int r = idx >> 5, c4 = idx & 31;
        int gr = row0 + r;
        gr = gr < nrows ? gr : nrows - 1;
        float4 v = *(const float4*)(A + (size_t)gr * 128 + c4 * 4);
        ushort4 b;
        b.x = (unsigned short)f2bf(v.x);
        b.y = (unsigned short)f2bf(v.y);
        b.z = (unsigned short)f2bf(v.z);
        b.w = (unsigned short)f2bf(v.w);
        *(ushort4*)(&As[r * LROW + c4 * 4]) = b;
    }
#pragma unroll
    for (int i = 0; i < 8; ++i) {
        int idx = tid + i * 256;
        int n = idx >> 4, kq = idx & 15;
        *(uint4*)(&Ws[n * LROW + kq * 8]) = *(const uint4*)(Wtl + n * 128 + kq * 8);
    }
    __syncthreads();

    bf16x8 af[4];
#pragma unroll
    for (int ks = 0; ks < 4; ++ks)
        af[ks] = *(const bf16x8*)(&As[(wave * 16 + m16) * LROW + ks * 32 + quad * 8]);

    f32x4 acc[8];
#pragma unroll
    for (int ct = 0; ct < 8; ++ct) acc[ct] = (f32x4){0.f, 0.f, 0.f, 0.f};
#pragma unroll
    for (int ct = 0; ct < 8; ++ct)
#pragma unroll
        for (int ks = 0; ks < 4; ++ks) {
            bf16x8 bf = *(const bf16x8*)(&Ws[(ct * 16 + m16) * LROW + ks * 32 + quad * 8]);
            acc[ct] = __builtin_amdgcn_mfma_f32_16x16x32_bf16(af[ks], bf, acc[ct], 0, 0, 0);
        }
#pragma unroll
    for (int ct = 0; ct < 8; ++ct)
#pragma unroll
        for (int r = 0; r < 4; ++r) {
            int grow = row0 + wave * 16 + quad * 4 + r;
            if (grow < nrows) xl[(size_t)grow * 128 + ct * 16 + m16] = (unsigned short)f2bf(acc[ct][r]);
        }

    __syncthreads();
#pragma unroll
    for (int i = 0; i < 8; ++i) {
        int idx = tid + i * 256;
        int n = idx >> 4, kq = idx & 15;
        *(uint4*)(&Ws[n * LROW + kq * 8]) = *(const uint4*)(Wtr + n * 128 + kq * 8);
    }
    __syncthreads();

#pragma unroll
    for (int ct = 0; ct < 8; ++ct) acc[ct] = (f32x4){0.f, 0.f, 0.f, 0.f};
#pragma unroll
    for (int ct = 0; ct < 8; ++ct)
#pragma unroll
        for (int ks = 0; ks < 4; ++ks) {
            bf16x8 bf = *(const bf16x8*)(&Ws[(ct * 16 + m16) * LROW + ks * 32 + quad * 8]);
            acc[ct] = __builtin_amdgcn_mfma_f32_16x16x32_bf16(af[ks], bf, acc[ct], 0, 0, 0);
        }
#pragma unroll
    for (int ct = 0; ct < 8; ++ct)
#pragma unroll
        for (int r = 0; r < 4; ++r) {
            int grow = row0 + wave * 16 + quad * 4 + r;
            if (grow < nrows) xr[(size_t)grow * 128 + ct * 16 + m16] = (unsigned short)f2bf(acc[ct][r]);
        }
}

// ---------------- 2-level scan (scanA fuses the column-sum of g) ----------------
#define SCAN_B 256
__global__ __launch_bounds__(SCAN_B) void scanA_k(const unsigned short* __restrict__ g, int n,
                                                  int* __restrict__ row_start,
                                                  int* __restrict__ bsum) {
    const int tid = threadIdx.x, lane = tid & 63, wid = tid >> 6;
    const int d = blockIdx.x * SCAN_B + tid;
    int v = 0;
    if (d < n) {
        unsigned s = 0;
#pragma unroll
        for (int c = 0; c < NCHUNK; ++c) s += g[(size_t)c * n + d];
        v = (int)s;
    }
    int inc = v;
#pragma unroll
    for (int dd = 1; dd < 64; dd <<= 1) {
        int t = __shfl_up(inc, dd);
        if (lane >= dd) inc += t;
    }
    __shared__ int wsum[SCAN_B / 64];
    if (lane == 63) wsum[wid] = inc;
    __syncthreads();
    int add = 0;
    for (int w = 0; w < wid; ++w) add += wsum[w];
    inc += add;
    if (d < n) row_start[d] = inc - v;
    if (tid == SCAN_B - 1) bsum[blockIdx.x] = inc;
}

__global__ __launch_bounds__(512) void scanB_k(int* __restrict__ bsum, int nb) {
    const int tid = threadIdx.x, lane = tid & 63, wid = tid >> 6;
    int v = (tid < nb) ? bsum[tid] : 0;
    int inc = v;
#pragma unroll
    for (int d = 1; d < 64; d <<= 1) {
        int t = __shfl_up(inc, d);
        if (lane >= d) inc += t;
    }
    __shared__ int wsum[8];
    if (lane == 63) wsum[wid] = inc;
    __syncthreads();
    int add = 0;
    for (int w = 0; w < wid; ++w) add += wsum[w];
    inc += add;
    if (tid < nb) bsum[tid] = inc - v;
}

// ------------- merged scanC + cbase: finalize row_start, emit bases -------------
__global__ __launch_bounds__(SCAN_B) void scanCb_k(int* __restrict__ row_start,
                                                   const int* __restrict__ bsum,
                                                   const unsigned short* __restrict__ g,
                                                   int N, int E,
                                                   int* __restrict__ src_sorted,
                                                   unsigned* __restrict__ base) {
    const int d = blockIdx.x * SCAN_B + threadIdx.x;
    if (blockIdx.x == 0 && threadIdx.x == 0) row_start[N] = E;
    if (blockIdx.x == 0 && threadIdx.x < 16) src_sorted[E + threadIdx.x] = 0;
    if (d >= N) return;
    unsigned run = (unsigned)(row_start[d] + bsum[blockIdx.x]);
    row_start[d] = (int)run;
#pragma unroll
    for (int c = 0; c < NCHUNK; ++c) {
        base[(size_t)c * N + d] = run;
        run += g[(size_t)c * N + d];
    }
}

// ------------- scatter via LDS cursors (no global atomics) -------------
__global__ __launch_bounds__(SORT_B) void scat_k(const int* __restrict__ src,
                                                 const int* __restrict__ dst, int E, int N,
                                                 int rsz, int chunk_e,
                                                 const unsigned* __restrict__ base,
                                                 int* __restrict__ src_sorted) {
    __shared__ unsigned lcur[MAX_RSZ];
    const int r = blockIdx.x & (NRANGE - 1);
    const int c = blockIdx.x >> 3;
    const unsigned r_lo = (unsigned)(r * rsz);
    const int e0 = c * chunk_e;
    const int e1 = min(e0 + chunk_e, E);

    const unsigned* bc = base + (size_t)c * N + r_lo;
    int lim = min(rsz, N - (int)r_lo);
    for (int i = threadIdx.x; i < lim; i += SORT_B) lcur[i] = bc[i];
    __syncthreads();

    int e_vec_end = e0;
    if (((((uintptr_t)(dst + e0)) | ((uintptr_t)(src + e0))) & 15) == 0) {
        const int nq = (e1 - e0) >> 2;
        const int4* dq = (const int4*)(dst + e0);
        const int4* sq = (const int4*)(src + e0);
        for (int q = (int)threadIdx.x; q < nq; q += SORT_B) {
            int4 d4 = dq[q];
            int4 s4 = sq[q];
            unsigned dd;
            dd = (unsigned)d4.x - r_lo;
            if (dd < (unsigned)rsz) { unsigned pos = atomicAdd(&lcur[dd], 1u); src_sorted[pos] = s4.x << 8; }
            dd = (unsigned)d4.y - r_lo;
            if (dd < (unsigned)rsz) { unsigned pos = atomicAdd(&lcur[dd], 1u); src_sorted[pos] = s4.y << 8; }
            dd = (unsigned)d4.z - r_lo;
            if (dd < (unsigned)rsz) { unsigned pos = atomicAdd(&lcur[dd], 1u); src_sorted[pos] = s4.z << 8; }
            dd = (unsigned)d4.w - r_lo;
            if (dd < (unsigned)rsz) { unsigned pos = atomicAdd(&lcur[dd], 1u); src_sorted[pos] = s4.w << 8; }
        }
        e_vec_end = e0 + (nq << 2);
    }
    for (int e = e_vec_end + (int)threadIdx.x; e < e1; e += SORT_B) {
        unsigned dd = (unsigned)dst[e] - r_lo;
        if (dd < (unsigned)rsz) {
            unsigned pos = atomicAdd(&lcur[dd], 1u);   // LDS atomic
            src_sorted[pos] = src[e] << 8;             // byte offset of xl row
        }
    }
}

// ---------------- aggregation: one wave per dst node (packed-f32 VALU) ----------------
// 16 lanes per edge (8 channels each); 8 edges per iteration in two 4-edge
// groups. Both src loads and both uint4 gathers issued before compute (2
// gathers in flight/lane). Padded indices clamped to 0 (L1-hot row 0); dead
// contributions die via the w=0 predicate. Channel math is f32x2-vectorized
// so the compiler emits v_pk_add_f32 / v_pk_mul_f32 / v_pk_fma_f32 (fmax has
// no packed form and stays scalar).
// att pre-scaled by log2(e): exp(e) == exp2(log2e*e) == one v_exp_f32.
__global__ __launch_bounds__(256) void agg_k(const unsigned* __restrict__ xlb,
                                             const unsigned* __restrict__ xrb,
                                             const float* __restrict__ att,
                                             const float* __restrict__ bias,
                                             const int* __restrict__ row_start,
                                             const int* __restrict__ src_sorted,
                                             int n, float* __restrict__ out) {
    const int wave = threadIdx.x >> 6;
    const int lane = threadIdx.x & 63;
    const int i = blockIdx.x * 4 + wave;
    if (i >= n) return;

    const int sub = lane & 15;
    const int eg  = lane >> 4;
    const int cb  = sub * 16;               // byte offset within a 256 B row
    const char* xb = (const char*)xlb;

    uint4 xrv = *(const uint4*)(xrb + (size_t)i * 64 + sub * 4);
    const f32x2 xr01 = {bflo(xrv.x), bfhi(xrv.x)};
    const f32x2 xr23 = {bflo(xrv.y), bfhi(xrv.y)};
    const f32x2 xr45 = {bflo(xrv.z), bfhi(xrv.z)};
    const f32x2 xr67 = {bflo(xrv.w), bfhi(xrv.w)};

    const float L2E = 1.44269504088896f;
    float4 a0 = *(const float4*)(att + sub * 8);
    float4 a1 = *(const float4*)(att + sub * 8 + 4);
    const f32x2 at01 = {a0.x * L2E, a0.y * L2E};
    const f32x2 at23 = {a0.z * L2E, a0.w * L2E};
    const f32x2 at45 = {a1.x * L2E, a1.y * L2E};
    const f32x2 at67 = {a1.z * L2E, a1.w * L2E};
    const f32x2 ns2 = {NEG_SLOPE, NEG_SLOPE};

    const int k0 = row_start[i];
    const int k1 = row_start[i + 1];

    float l = 0.f;
    f32x2 Ac01 = {0.f, 0.f}, Ac23 = {0.f, 0.f};
    f32x2 Ac45 = {0.f, 0.f}, Ac67 = {0.f, 0.f};

#define PROC_GRP(V, OFF)                                                       \
    {                                                                          \
        f32x2 x01 = {bflo(V.x), bfhi(V.x)};                                    \
        f32x2 x23 = {bflo(V.y), bfhi(V.y)};                                    \
        f32x2 x45 = {bflo(V.z), bfhi(V.z)};                                    \
        f32x2 x67 = {bflo(V.w), bfhi(V.w)};                                    \
        f32x2 h01 = x01 + xr01, h23 = x23 + xr23;                              \
        f32x2 h45 = x45 + xr45, h67 = x67 + xr67;                              \
        f32x2 m01 = h01 * ns2, m23 = h23 * ns2;                                \
        f32x2 m45 = h45 * ns2, m67 = h67 * ns2;                                \
        f32x2 t01 = {fmaxf(h01.x, m01.x), fmaxf(h01.y, m01.y)};                \
        f32x2 t23 = {fmaxf(h23.x, m23.x), fmaxf(h23.y, m23.y)};                \
        f32x2 t45 = {fmaxf(h45.x, m45.x), fmaxf(h45.y, m45.y)};                \
        f32x2 t67 = {fmaxf(h67.x, m67.x), fmaxf(h67.y, m67.y)};                \
        f32x2 pa = at01 * t01;                                                 \
        pa = __builtin_elementwise_fma(at23, t23, pa);                         \
        pa = __builtin_elementwise_fma(at45, t45, pa);                         \
        pa = __builtin_elementwise_fma(at67, t67, pa);                         \
        float p = pa.x + pa.y;                                                 \
        p += __shfl_xor(p, 1);                                                 \
        p += __shfl_xor(p, 2);                                                 \
        float w;                                                               \
        asm("v_exp_f32 %0, %1" : "=v"(w) : "v"(p));                            \
        w = (k + (OFF) + eg < k1) ? w : 0.f;                                   \
        l += w;                                                                \
        f32x2 w2 = {w, w};                                                     \
        Ac01 = __builtin_elementwise_fma(w2, x01, Ac01);                       \
        Ac23 = __builtin_elementwise_fma(w2, x23, Ac23);                       \
        Ac45 = __builtin_elementwise_fma(w2, x45, Ac45);                       \
        Ac67 = __builtin_elementwise_fma(w2, x67, Ac67);                       \
    }

    for (int k = k0; k < k1; k += 8) {
        // ---- issue all memory ops first (MLP); clamp dead gathers to row 0 ----
        int sA = src_sorted[k + eg];
        int sB = src_sorted[k + 4 + eg];
        sA = (k + eg < k1) ? sA : 0;
        sB = (k + 4 + eg < k1) ? sB : 0;
        uint4 vA = *(const uint4*)(xb + (unsigned)sA + cb);
        uint4 vB = *(const uint4*)(xb + (unsigned)sB + cb);

        PROC_GRP(vA, 0)
        PROC_GRP(vB, 4)
    }
#undef PROC_GRP

    float A0 = Ac01.x, A1 = Ac01.y, A2 = Ac23.x, A3 = Ac23.y;
    float A4 = Ac45.x, A5 = Ac45.y, A6 = Ac67.x, A7 = Ac67.y;

    l  += __shfl_xor(l, 16);  l  += __shfl_xor(l, 32);
    A0 += __shfl_xor(A0, 16); A0 += __shfl_xor(A0, 32);
    A1 += __shfl_xor(A1, 16); A1 += __shfl_xor(A1, 32);
    A2 += __shfl_xor(A2, 16); A2 += __shfl_xor(A2, 32);
    A3 += __shfl_xor(A3, 16); A3 += __shfl_xor(A3, 32);
    A4 += __shfl_xor(A4, 16); A4 += __shfl_xor(A4, 32);
    A5 += __shfl_xor(A5, 16); A5 += __shfl_xor(A5, 32);
    A6 += __shfl_xor(A6, 16); A6 += __shfl_xor(A6, 32);
    A7 += __shfl_xor(A7, 16); A7 += __shfl_xor(A7, 32);

    if (eg == 0) {
        float inv = 1.f / (l + EPS_F);
        float4 b0 = *(const float4*)(bias + sub * 8);
        float4 b1 = *(const float4*)(bias + sub * 8 + 4);
        float4 o0 = {fmaf(A0, inv, b0.x), fmaf(A1, inv, b0.y),
                     fmaf(A2, inv, b0.z), fmaf(A3, inv, b0.w)};
        float4 o1 = {fmaf(A4, inv, b1.x), fmaf(A5, inv, b1.y),
                     fmaf(A6, inv, b1.z), fmaf(A7, inv, b1.w)};
        *(float4*)(out + (size_t)i * 128 + sub * 8)     = o0;
        *(float4*)(out + (size_t)i * 128 + sub * 8 + 4) = o1;
    }
}

// ---------------- launch ----------------
extern "C" void kernel_launch(void* const* d_in, const int* in_sizes, int n_in,
                              void* d_out, int out_size, void* d_ws, size_t ws_size,
                              hipStream_t stream) {
    const float* x    = (const float*)d_in[0];
    const int*   ei   = (const int*)d_in[1];
    const float* W_l  = (const float*)d_in[2];
    const float* W_r  = (const float*)d_in[3];
    const float* att  = (const float*)d_in[4];
    const float* bias = (const float*)d_in[5];
    float* out = (float*)d_out;

    const int N = in_sizes[0] / 128;
    const int E = in_sizes[1] / 2;
    const int* src = ei;
    const int* dst = ei + E;

    char* ws = (char*)d_ws;
    size_t off = 0;
    auto alloc = [&](size_t bytes) {
        void* p = ws + off;
        off += (bytes + 15) & ~(size_t)15;
        return p;
    };
    unsigned* xlb       = (unsigned*)alloc((size_t)N * 64 * 4);        // bf16 [N][128]
    unsigned* xrb       = (unsigned*)alloc((size_t)N * 64 * 4);
    unsigned short* g   = (unsigned short*)alloc((size_t)NCHUNK * N * 2);  // 6.4 MB
    unsigned* base      = (unsigned*)alloc((size_t)NCHUNK * N * 4);        // 12.8 MB
    int* row_start      = (int*)alloc((size_t)(N + 1) * 4);
    const int nsb = (N + SCAN_B - 1) / SCAN_B;
    int* bsum           = (int*)alloc((size_t)nsb * 4);
    int* src_sorted     = (int*)alloc((size_t)(E + 16) * 4);
    unsigned short* Wtl = (unsigned short*)alloc((size_t)128 * 128 * 2);
    unsigned short* Wtr = (unsigned short*)alloc((size_t)128 * 128 * 2);
    (void)ws_size;

    const int rsz = (N + NRANGE - 1) / NRANGE;              // 12500 (<= MAX_RSZ)
    int chunk_e = (E + NCHUNK - 1) / NCHUNK;                // 50000 (< 65536: u16 safe)
    chunk_e = (chunk_e + 3) & ~3;                           // 16B-align chunk starts

    histW_k<<<NRANGE * NCHUNK + 1, SORT_B, 0, stream>>>(dst, E, N, rsz, chunk_e, g,
                                                        W_l, W_r, Wtl, Wtr);

    const int gB = (N + 63) / 64;
    mfma_gemm_k<<<gB, 256, 0, stream>>>(x, Wtl, Wtr,
                                        (unsigned short*)xlb, (unsigned short*)xrb, N);

    scanA_k<<<nsb, SCAN_B, 0, stream>>>(g, N, row_start, bsum);
    scanB_k<<<1, 512, 0, stream>>>(bsum, nsb);
    scanCb_k<<<nsb, SCAN_B, 0, stream>>>(row_start, bsum, g, N, E, src_sorted, base);

    scat_k<<<NRANGE * NCHUNK, SORT_B, 0, stream>>>(src, dst, E, N, rsz, chunk_e,
                                                   base, src_sorted);

    agg_k<<<(N + 3) / 4, 256, 0, stream>>>(xlb, xrb, att, bias, row_start, src_sorted, N, out);
}

// Round 13
// 256.743 us; speedup vs baseline: 1.0659x; 1.0659x over previous
//
#include <hip/hip_runtime.h>
#include <hip/hip_bf16.h>
#include <cstdint>
#include <cstddef>

// GATv2Conv forward, N=100000, E=1.6M, IN=128, H=4, C=32 (H*C=128).
//
// Pipeline — deterministic CSR build with ZERO global atomics (measured: 1.6M
// device-scope atomics cost >100 µs on MI355X; LDS atomics are ~free).
// Measured lessons: (r8) exact-fill persistent grids drain badly on irregular
// work; (r5-r10) agg sweet spot is stride-8 / 2-gathers-in-flight at high
// occupancy; (r10) padded gathers clamped to row 0 (L1-hot); (r12) packed
// f32x2 VALU rewrite REGRESSED (79->87 µs, VALUBusy 82->61%) — scalar form
// with 2 shuffles/group is the measured VALU floor for this structure.
//   1) histW_k  : 8 ranges x 32 chunks, 1024-thr blocks; LDS u32 histogram of
//                 dst within range -> g[c][d] as u16. int4-vectorized edge
//                 reads. +1 block: W -> bf16 Wt.
//   2) mfma_gemm_k : xl = x@W_l, xr = x@W_r via v_mfma_f32_16x16x32_bf16.
//   3) scanA(fused colsum) -> scanCb_k (merged scanB+scanC+cbase: each block
//                 reduces bsum[0..blockIdx) itself — 391 L2-hot ints).
//   4) scat_k   : LDS cursors seeded from base, LDS atomicAdd, direct store.
//                 blockIdx&7 == range -> XCD affinity. int4-vectorized.
//   5) agg_k    : one wave per dst node; 16 lanes/edge (8 ch each), 8 edges/
//                 iter in two 4-edge groups, both gathers + src loads issued
//                 up front; padded gather indices clamped to 0.
//                 att pre-scaled by log2(e) so softmax exp = one v_exp_f32.

#define NEG_SLOPE 0.2f
#define EPS_F 1e-16f
#define NRANGE 8
#define NCHUNK 32
#define SORT_B 1024
#define MAX_RSZ 12512   // >= ceil(N/NRANGE); LDS = 50 KB (u32)

typedef __attribute__((ext_vector_type(8))) short bf16x8;
typedef __attribute__((ext_vector_type(4))) float f32x4;

static __device__ __forceinline__ unsigned f2bf(float f) {
    unsigned u = __float_as_uint(f);
    return (u + 0x7fffu + ((u >> 16) & 1u)) >> 16;   // RNE
}
static __device__ __forceinline__ float bf2f(unsigned h) {
    return __uint_as_float(h << 16);
}
static __device__ __forceinline__ float bflo(unsigned u) {
    return __uint_as_float(u << 16);                 // low bf16 of a u32 pair
}
static __device__ __forceinline__ float bfhi(unsigned u) {
    return __uint_as_float(u & 0xffff0000u);         // high bf16 of a u32 pair
}

// ------------- LDS-histogram pass + W transpose -------------
__global__ __launch_bounds__(SORT_B) void histW_k(const int* __restrict__ dst, int E, int N,
                                                  int rsz, int chunk_e,
                                                  unsigned short* __restrict__ g,
                                                  const float* __restrict__ Wl,
                                                  const float* __restrict__ Wr,
                                                  unsigned short* __restrict__ Wtl,
                                                  unsigned short* __restrict__ Wtr) {
    if (blockIdx.x == NRANGE * NCHUNK) {
        for (int mat = 0; mat < 2; ++mat) {
            const float* W = mat ? Wr : Wl;
            unsigned short* Wt = mat ? Wtr : Wtl;
            for (int i = 0; i < 16; ++i) {
                int idx = (int)threadIdx.x + i * SORT_B;
                int k = idx >> 7, n = idx & 127;
                Wt[n * 128 + k] = (unsigned short)f2bf(W[idx]);
            }
        }
        return;
    }
    __shared__ unsigned lcnt[MAX_RSZ];
    const int r = blockIdx.x & (NRANGE - 1);
    const int c = blockIdx.x >> 3;
    const unsigned r_lo = (unsigned)(r * rsz);
    const int e0 = c * chunk_e;
    const int e1 = min(e0 + chunk_e, E);

    for (int i = threadIdx.x; i < rsz; i += SORT_B) lcnt[i] = 0u;
    __syncthreads();

    int e_vec_end = e0;
    if ((((uintptr_t)(dst + e0)) & 15) == 0) {          // int4-aligned fast path
        const int nq = (e1 - e0) >> 2;
        const int4* dq = (const int4*)(dst + e0);
        for (int q = (int)threadIdx.x; q < nq; q += SORT_B) {
            int4 d4 = dq[q];
            unsigned dd;
            dd = (unsigned)d4.x - r_lo; if (dd < (unsigned)rsz) atomicAdd(&lcnt[dd], 1u);
            dd = (unsigned)d4.y - r_lo; if (dd < (unsigned)rsz) atomicAdd(&lcnt[dd], 1u);
            dd = (unsigned)d4.z - r_lo; if (dd < (unsigned)rsz) atomicAdd(&lcnt[dd], 1u);
            dd = (unsigned)d4.w - r_lo; if (dd < (unsigned)rsz) atomicAdd(&lcnt[dd], 1u);
        }
        e_vec_end = e0 + (nq << 2);
    }
    for (int e = e_vec_end + (int)threadIdx.x; e < e1; e += SORT_B) {
        unsigned dd = (unsigned)dst[e] - r_lo;
        if (dd < (unsigned)rsz) atomicAdd(&lcnt[dd], 1u);   // LDS atomic
    }
    __syncthreads();
    unsigned short* gc = g + (size_t)c * N + r_lo;
    int lim = min(rsz, N - (int)r_lo);
    for (int i = threadIdx.x; i < lim; i += SORT_B) gc[i] = (unsigned short)lcnt[i];
}

// ------------- MFMA GEMM: xl = x@Wl, xr = x@Wr (bf16 in, bf16 out) -------------
#define LROW 136
__global__ __launch_bounds__(256) void mfma_gemm_k(const float* __restrict__ A,
                                                   const unsigned short* __restrict__ Wtl,
                                                   const unsigned short* __restrict__ Wtr,
                                                   unsigned short* __restrict__ xl,
                                                   unsigned short* __restrict__ xr,
                                                   int nrows) {
    __shared__ unsigned short As[64 * LROW];
    __shared__ unsigned short Ws[128 * LROW];
    const int tid = threadIdx.x;
    const int wave = tid >> 6, lane = tid & 63;
    const int quad = lane >> 4, m16 = lane & 15;
    const int row0 = blockIdx.x * 64;

#pragma unroll
    for (int i = 0; i < 8; ++i) {
        int idx = tid + i * 256;
        int r = idx >> 5, c4 = idx & 31;
        int gr = row0 + r;
        gr = gr < nrows ? gr : nrows - 1;
        float4 v = *(const float4*)(A + (size_t)gr * 128 + c4 * 4);
        ushort4 b;
        b.x = (unsigned short)f2bf(v.x);
        b.y = (unsigned short)f2bf(v.y);
        b.z = (unsigned short)f2bf(v.z);
        b.w = (unsigned short)f2bf(v.w);
        *(ushort4*)(&As[r * LROW + c4 * 4]) = b;
    }
#pragma unroll
    for (int i = 0; i < 8; ++i) {
        int idx = tid + i * 256;
        int n = idx >> 4, kq = idx & 15;
        *(uint4*)(&Ws[n * LROW + kq * 8]) = *(const uint4*)(Wtl + n * 128 + kq * 8);
    }
    __syncthreads();

    bf16x8 af[4];
#pragma unroll
    for (int ks = 0; ks < 4; ++ks)
        af[ks] = *(const bf16x8*)(&As[(wave * 16 + m16) * LROW + ks * 32 + quad * 8]);

    f32x4 acc[8];
#pragma unroll
    for (int ct = 0; ct < 8; ++ct) acc[ct] = (f32x4){0.f, 0.f, 0.f, 0.f};
#pragma unroll
    for (int ct = 0; ct < 8; ++ct)
#pragma unroll
        for (int ks = 0; ks < 4; ++ks) {
            bf16x8 bf = *(const bf16x8*)(&Ws[(ct * 16 + m16) * LROW + ks * 32 + quad * 8]);
            acc[ct] = __builtin_amdgcn_mfma_f32_16x16x32_bf16(af[ks], bf, acc[ct], 0, 0, 0);
        }
#pragma unroll
    for (int ct = 0; ct < 8; ++ct)
#pragma unroll
        for (int r = 0; r < 4; ++r) {
            int grow = row0 + wave * 16 + quad * 4 + r;
            if (grow < nrows) xl[(size_t)grow * 128 + ct * 16 + m16] = (unsigned short)f2bf(acc[ct][r]);
        }

    __syncthreads();
#pragma unroll
    for (int i = 0; i < 8; ++i) {
        int idx = tid + i * 256;
        int n = idx >> 4, kq = idx & 15;
        *(uint4*)(&Ws[n * LROW + kq * 8]) = *(const uint4*)(Wtr + n * 128 + kq * 8);
    }
    __syncthreads();

#pragma unroll
    for (int ct = 0; ct < 8; ++ct) acc[ct] = (f32x4){0.f, 0.f, 0.f, 0.f};
#pragma unroll
    for (int ct = 0; ct < 8; ++ct)
#pragma unroll
        for (int ks = 0; ks < 4; ++ks) {
            bf16x8 bf = *(const bf16x8*)(&Ws[(ct * 16 + m16) * LROW + ks * 32 + quad * 8]);
            acc[ct] = __builtin_amdgcn_mfma_f32_16x16x32_bf16(af[ks], bf, acc[ct], 0, 0, 0);
        }
#pragma unroll
    for (int ct = 0; ct < 8; ++ct)
#pragma unroll
        for (int r = 0; r < 4; ++r) {
            int grow = row0 + wave * 16 + quad * 4 + r;
            if (grow < nrows) xr[(size_t)grow * 128 + ct * 16 + m16] = (unsigned short)f2bf(acc[ct][r]);
        }
}

// ---------------- scanA: fused column-sum of g + per-block exclusive scan ----------------
#define SCAN_B 256
__global__ __launch_bounds__(SCAN_B) void scanA_k(const unsigned short* __restrict__ g, int n,
                                                  int* __restrict__ row_start,
                                                  int* __restrict__ bsum) {
    const int tid = threadIdx.x, lane = tid & 63, wid = tid >> 6;
    const int d = blockIdx.x * SCAN_B + tid;
    int v = 0;
    if (d < n) {
        unsigned s = 0;
#pragma unroll
        for (int c = 0; c < NCHUNK; ++c) s += g[(size_t)c * n + d];
        v = (int)s;
    }
    int inc = v;
#pragma unroll
    for (int dd = 1; dd < 64; dd <<= 1) {
        int t = __shfl_up(inc, dd);
        if (lane >= dd) inc += t;
    }
    __shared__ int wsum[SCAN_B / 64];
    if (lane == 63) wsum[wid] = inc;
    __syncthreads();
    int add = 0;
    for (int w = 0; w < wid; ++w) add += wsum[w];
    inc += add;
    if (d < n) row_start[d] = inc - v;
    if (tid == SCAN_B - 1) bsum[blockIdx.x] = inc;
}

// ------------- merged scanB + scanC + cbase: each block reduces its own prefix -------------
// bsum[] holds per-block inclusive totals from scanA; block b's offset is
// sum(bsum[0..b)) — <=391 L2-hot ints, reduced by 256 threads in ~1 µs total.
__global__ __launch_bounds__(SCAN_B) void scanCb_k(int* __restrict__ row_start,
                                                   const int* __restrict__ bsum,
                                                   const unsigned short* __restrict__ g,
                                                   int N, int E,
                                                   int* __restrict__ src_sorted,
                                                   unsigned* __restrict__ base) {
    const int tid = threadIdx.x;
    const int lane = tid & 63, wid = tid >> 6;
    // ---- block-prefix reduction (ALL threads; no early return before barrier) ----
    int partial = 0;
    for (int w = tid; w < (int)blockIdx.x; w += SCAN_B) partial += bsum[w];
#pragma unroll
    for (int dd = 1; dd < 64; dd <<= 1) partial += __shfl_xor(partial, dd);
    __shared__ int wred[SCAN_B / 64];
    if (lane == 0) wred[wid] = partial;
    __syncthreads();
    int add = 0;
#pragma unroll
    for (int w = 0; w < SCAN_B / 64; ++w) add += wred[w];

    const int d = blockIdx.x * SCAN_B + tid;
    if (blockIdx.x == 0 && tid == 0) row_start[N] = E;
    if (blockIdx.x == 0 && tid < 16) src_sorted[E + tid] = 0;
    if (d >= N) return;
    unsigned run = (unsigned)(row_start[d] + add);
    row_start[d] = (int)run;
#pragma unroll
    for (int c = 0; c < NCHUNK; ++c) {
        base[(size_t)c * N + d] = run;
        run += g[(size_t)c * N + d];
    }
}

// ------------- scatter via LDS cursors (no global atomics) -------------
__global__ __launch_bounds__(SORT_B) void scat_k(const int* __restrict__ src,
                                                 const int* __restrict__ dst, int E, int N,
                                                 int rsz, int chunk_e,
                                                 const unsigned* __restrict__ base,
                                                 int* __restrict__ src_sorted) {
    __shared__ unsigned lcur[MAX_RSZ];
    const int r = blockIdx.x & (NRANGE - 1);
    const int c = blockIdx.x >> 3;
    const unsigned r_lo = (unsigned)(r * rsz);
    const int e0 = c * chunk_e;
    const int e1 = min(e0 + chunk_e, E);

    const unsigned* bc = base + (size_t)c * N + r_lo;
    int lim = min(rsz, N - (int)r_lo);
    for (int i = threadIdx.x; i < lim; i += SORT_B) lcur[i] = bc[i];
    __syncthreads();

    int e_vec_end = e0;
    if (((((uintptr_t)(dst + e0)) | ((uintptr_t)(src + e0))) & 15) == 0) {
        const int nq = (e1 - e0) >> 2;
        const int4* dq = (const int4*)(dst + e0);
        const int4* sq = (const int4*)(src + e0);
        for (int q = (int)threadIdx.x; q < nq; q += SORT_B) {
            int4 d4 = dq[q];
            int4 s4 = sq[q];
            unsigned dd;
            dd = (unsigned)d4.x - r_lo;
            if (dd < (unsigned)rsz) { unsigned pos = atomicAdd(&lcur[dd], 1u); src_sorted[pos] = s4.x << 8; }
            dd = (unsigned)d4.y - r_lo;
            if (dd < (unsigned)rsz) { unsigned pos = atomicAdd(&lcur[dd], 1u); src_sorted[pos] = s4.y << 8; }
            dd = (unsigned)d4.z - r_lo;
            if (dd < (unsigned)rsz) { unsigned pos = atomicAdd(&lcur[dd], 1u); src_sorted[pos] = s4.z << 8; }
            dd = (unsigned)d4.w - r_lo;
            if (dd < (unsigned)rsz) { unsigned pos = atomicAdd(&lcur[dd], 1u); src_sorted[pos] = s4.w << 8; }
        }
        e_vec_end = e0 + (nq << 2);
    }
    for (int e = e_vec_end + (int)threadIdx.x; e < e1; e += SORT_B) {
        unsigned dd = (unsigned)dst[e] - r_lo;
        if (dd < (unsigned)rsz) {
            unsigned pos = atomicAdd(&lcur[dd], 1u);   // LDS atomic
            src_sorted[pos] = src[e] << 8;             // byte offset of xl row
        }
    }
}

// ---------------- aggregation: one wave per dst node (r11-proven scalar) ----------------
// 16 lanes per edge (8 channels each); 8 edges per iteration in two 4-edge
// groups (A: k+eg, B: k+4+eg). Both src loads and both uint4 gathers are
// issued before any compute -> 2 gathers + 2 src loads in flight per lane.
// Padded edge indices (>= k1) are CLAMPED to 0 so dead gathers hit the
// L1-resident row 0; their contributions die via the w=0 predicate.
// att pre-scaled by log2(e): exp(e) == exp2(log2e*e) == one v_exp_f32.
__global__ __launch_bounds__(256) void agg_k(const unsigned* __restrict__ xlb,
                                             const unsigned* __restrict__ xrb,
                                             const float* __restrict__ att,
                                             const float* __restrict__ bias,
                                             const int* __restrict__ row_start,
                                             const int* __restrict__ src_sorted,
                                             int n, float* __restrict__ out) {
    const int wave = threadIdx.x >> 6;
    const int lane = threadIdx.x & 63;
    const int i = blockIdx.x * 4 + wave;
    if (i >= n) return;

    const int sub = lane & 15;
    const int eg  = lane >> 4;
    const int cb  = sub * 16;               // byte offset within a 256 B row
    const char* xb = (const char*)xlb;

    uint4 xrv = *(const uint4*)(xrb + (size_t)i * 64 + sub * 4);
    const float xr0 = bflo(xrv.x), xr1 = bfhi(xrv.x);
    const float xr2 = bflo(xrv.y), xr3 = bfhi(xrv.y);
    const float xr4 = bflo(xrv.z), xr5 = bfhi(xrv.z);
    const float xr6 = bflo(xrv.w), xr7 = bfhi(xrv.w);

    const float L2E = 1.44269504088896f;
    float4 atA = *(const float4*)(att + sub * 8);
    float4 atB = *(const float4*)(att + sub * 8 + 4);
    atA.x *= L2E; atA.y *= L2E; atA.z *= L2E; atA.w *= L2E;
    atB.x *= L2E; atB.y *= L2E; atB.z *= L2E; atB.w *= L2E;

    const int k0 = row_start[i];
    const int k1 = row_start[i + 1];

    float l = 0.f;
    float A0 = 0.f, A1 = 0.f, A2 = 0.f, A3 = 0.f;
    float A4 = 0.f, A5 = 0.f, A6 = 0.f, A7 = 0.f;

    for (int k = k0; k < k1; k += 8) {
        // ---- issue all memory ops first (MLP); clamp dead gathers to row 0 ----
        int sA = src_sorted[k + eg];
        int sB = src_sorted[k + 4 + eg];
        sA = (k + eg < k1) ? sA : 0;
        sB = (k + 4 + eg < k1) ? sB : 0;
        uint4 vA = *(const uint4*)(xb + (unsigned)sA + cb);
        uint4 vB = *(const uint4*)(xb + (unsigned)sB + cb);

        // ---- group A ----
        {
            float x0 = bflo(vA.x), x1 = bfhi(vA.x);
            float x2 = bflo(vA.y), x3 = bfhi(vA.y);
            float x4 = bflo(vA.z), x5 = bfhi(vA.z);
            float x6 = bflo(vA.w), x7 = bfhi(vA.w);
            float h0 = x0 + xr0, h1 = x1 + xr1, h2 = x2 + xr2, h3 = x3 + xr3;
            float h4 = x4 + xr4, h5 = x5 + xr5, h6 = x6 + xr6, h7 = x7 + xr7;
            float t, p;
            t = fmaxf(h0, NEG_SLOPE * h0); p = atA.x * t;
            t = fmaxf(h1, NEG_SLOPE * h1); p = fmaf(atA.y, t, p);
            t = fmaxf(h2, NEG_SLOPE * h2); p = fmaf(atA.z, t, p);
            t = fmaxf(h3, NEG_SLOPE * h3); p = fmaf(atA.w, t, p);
            t = fmaxf(h4, NEG_SLOPE * h4); p = fmaf(atB.x, t, p);
            t = fmaxf(h5, NEG_SLOPE * h5); p = fmaf(atB.y, t, p);
            t = fmaxf(h6, NEG_SLOPE * h6); p = fmaf(atB.z, t, p);
            t = fmaxf(h7, NEG_SLOPE * h7); p = fmaf(atB.w, t, p);
            p += __shfl_xor(p, 1);
            p += __shfl_xor(p, 2);           // p = e[head], replicated in 4 lanes
            float w;
            asm("v_exp_f32 %0, %1" : "=v"(w) : "v"(p));   // 2^p == exp(e)
            w = (k + eg < k1) ? w : 0.f;
            l += w;
            A0 = fmaf(w, x0, A0); A1 = fmaf(w, x1, A1);
            A2 = fmaf(w, x2, A2); A3 = fmaf(w, x3, A3);
            A4 = fmaf(w, x4, A4); A5 = fmaf(w, x5, A5);
            A6 = fmaf(w, x6, A6); A7 = fmaf(w, x7, A7);
        }
        // ---- group B ----
        {
            float x0 = bflo(vB.x), x1 = bfhi(vB.x);
            float x2 = bflo(vB.y), x3 = bfhi(vB.y);
            float x4 = bflo(vB.z), x5 = bfhi(vB.z);
            float x6 = bflo(vB.w), x7 = bfhi(vB.w);
            float h0 = x0 + xr0, h1 = x1 + xr1, h2 = x2 + xr2, h3 = x3 + xr3;
            float h4 = x4 + xr4, h5 = x5 + xr5, h6 = x6 + xr6, h7 = x7 + xr7;
            float t, p;
            t = fmaxf(h0, NEG_SLOPE * h0); p = atA.x * t;
            t = fmaxf(h1, NEG_SLOPE * h1); p = fmaf(atA.y, t, p);
            t = fmaxf(h2, NEG_SLOPE * h2); p = fmaf(atA.z, t, p);
            t = fmaxf(h3, NEG_SLOPE * h3); p = fmaf(atA.w, t, p);
            t = fmaxf(h4, NEG_SLOPE * h4); p = fmaf(atB.x, t, p);
            t = fmaxf(h5, NEG_SLOPE * h5); p = fmaf(atB.y, t, p);
            t = fmaxf(h6, NEG_SLOPE * h6); p = fmaf(atB.z, t, p);
            t = fmaxf(h7, NEG_SLOPE * h7); p = fmaf(atB.w, t, p);
            p += __shfl_xor(p, 1);
            p += __shfl_xor(p, 2);
            float w;
            asm("v_exp_f32 %0, %1" : "=v"(w) : "v"(p));
            w = (k + 4 + eg < k1) ? w : 0.f;
            l += w;
            A0 = fmaf(w, x0, A0); A1 = fmaf(w, x1, A1);
            A2 = fmaf(w, x2, A2); A3 = fmaf(w, x3, A3);
            A4 = fmaf(w, x4, A4); A5 = fmaf(w, x5, A5);
            A6 = fmaf(w, x6, A6); A7 = fmaf(w, x7, A7);
        }
    }

    l  += __shfl_xor(l, 16);  l  += __shfl_xor(l, 32);
    A0 += __shfl_xor(A0, 16); A0 += __shfl_xor(A0, 32);
    A1 += __shfl_xor(A1, 16); A1 += __shfl_xor(A1, 32);
    A2 += __shfl_xor(A2, 16); A2 += __shfl_xor(A2, 32);
    A3 += __shfl_xor(A3, 16); A3 += __shfl_xor(A3, 32);
    A4 += __shfl_xor(A4, 16); A4 += __shfl_xor(A4, 32);
    A5 += __shfl_xor(A5, 16); A5 += __shfl_xor(A5, 32);
    A6 += __shfl_xor(A6, 16); A6 += __shfl_xor(A6, 32);
    A7 += __shfl_xor(A7, 16); A7 += __shfl_xor(A7, 32);

    if (eg == 0) {
        float inv = 1.f / (l + EPS_F);
        float4 b0 = *(const float4*)(bias + sub * 8);
        float4 b1 = *(const float4*)(bias + sub * 8 + 4);
        float4 o0 = {fmaf(A0, inv, b0.x), fmaf(A1, inv, b0.y),
                     fmaf(A2, inv, b0.z), fmaf(A3, inv, b0.w)};
        float4 o1 = {fmaf(A4, inv, b1.x), fmaf(A5, inv, b1.y),
                     fmaf(A6, inv, b1.z), fmaf(A7, inv, b1.w)};
        *(float4*)(out + (size_t)i * 128 + sub * 8)     = o0;
        *(float4*)(out + (size_t)i * 128 + sub * 8 + 4) = o1;
    }
}

// ---------------- launch ----------------
extern "C" void kernel_launch(void* const* d_in, const int* in_sizes, int n_in,
                              void* d_out, int out_size, void* d_ws, size_t ws_size,
                              hipStream_t stream) {
    const float* x    = (const float*)d_in[0];
    const int*   ei   = (const int*)d_in[1];
    const float* W_l  = (const float*)d_in[2];
    const float* W_r  = (const float*)d_in[3];
    const float* att  = (const float*)d_in[4];
    const float* bias = (const float*)d_in[5];
    float* out = (float*)d_out;

    const int N = in_sizes[0] / 128;
    const int E = in_sizes[1] / 2;
    const int* src = ei;
    const int* dst = ei + E;

    char* ws = (char*)d_ws;
    size_t off = 0;
    auto alloc = [&](size_t bytes) {
        void* p = ws + off;
        off += (bytes + 15) & ~(size_t)15;
        return p;
    };
    unsigned* xlb       = (unsigned*)alloc((size_t)N * 64 * 4);        // bf16 [N][128]
    unsigned* xrb       = (unsigned*)alloc((size_t)N * 64 * 4);
    unsigned short* g   = (unsigned short*)alloc((size_t)NCHUNK * N * 2);  // 6.4 MB
    unsigned* base      = (unsigned*)alloc((size_t)NCHUNK * N * 4);        // 12.8 MB
    int* row_start      = (int*)alloc((size_t)(N + 1) * 4);
    const int nsb = (N + SCAN_B - 1) / SCAN_B;
    int* bsum           = (int*)alloc((size_t)nsb * 4);
    int* src_sorted     = (int*)alloc((size_t)(E + 16) * 4);
    unsigned short* Wtl = (unsigned short*)alloc((size_t)128 * 128 * 2);
    unsigned short* Wtr = (unsigned short*)alloc((size_t)128 * 128 * 2);
    (void)ws_size;

    const int rsz = (N + NRANGE - 1) / NRANGE;              // 12500 (<= MAX_RSZ)
    int chunk_e = (E + NCHUNK - 1) / NCHUNK;                // 50000 (< 65536: u16 safe)
    chunk_e = (chunk_e + 3) & ~3;                           // 16B-align chunk starts

    histW_k<<<NRANGE * NCHUNK + 1, SORT_B, 0, stream>>>(dst, E, N, rsz, chunk_e, g,
                                                        W_l, W_r, Wtl, Wtr);

    const int gB = (N + 63) / 64;
    mfma_gemm_k<<<gB, 256, 0, stream>>>(x, Wtl, Wtr,
                                        (unsigned short*)xlb, (unsigned short*)xrb, N);

    scanA_k<<<nsb, SCAN_B, 0, stream>>>(g, N, row_start, bsum);
    scanCb_k<<<nsb, SCAN_B, 0, stream>>>(row_start, bsum, g, N, E, src_sorted, base);

    scat_k<<<NRANGE * NCHUNK, SORT_B, 0, stream>>>(src, dst, E, N, rsz, chunk_e,
                                                   base, src_sorted);

    agg_k<<<(N + 3) / 4, 256, 0, stream>>>(xlb, xrb, att, bias, row_start, src_sorted, N, out);
}

// Round 14
// 251.618 us; speedup vs baseline: 1.0877x; 1.0204x over previous
//
#include <hip/hip_runtime.h>
#include <hip/hip_bf16.h>
#include <cstdint>
#include <cstddef>

// GATv2Conv forward, N=100000, E=1.6M, IN=128, H=4, C=32 (H*C=128).
//
// Pipeline — deterministic CSR build with ZERO global atomics (measured: 1.6M
// device-scope atomics cost >100 µs on MI355X; LDS atomics are ~free).
// Measured lessons: (r8) exact-fill persistent grids drain badly on irregular
// work; (r5-r10) agg sweet spot is stride-8 / 2-gathers-in-flight at high
// occupancy; (r10) padded gathers clamped to row 0 (L1-hot); (r12) packed
// f32x2 VALU rewrite REGRESSED — scalar form is the VALU floor; (r13) agg at
// 64% occupancy with no static limiter -> workgroup-granularity wave-slot
// release + degree imbalance; this round: 128-thread agg blocks (2 waves)
// to halve the imbalance granularity.
//   1) histW_k  : 8 ranges x 32 chunks, 1024-thr blocks; LDS u32 histogram of
//                 dst within range -> g[c][d] as u16. int4-vectorized edge
//                 reads. +1 block: W -> bf16 Wt.
//   2) mfma_gemm_k : xl = x@W_l, xr = x@W_r via v_mfma_f32_16x16x32_bf16.
//   3) scanA(fused colsum) -> scanCb_k (merged scanB+scanC+cbase: each block
//                 reduces bsum[0..blockIdx) itself — 391 L2-hot ints).
//   4) scat_k   : LDS cursors seeded from base, LDS atomicAdd, direct store.
//                 blockIdx&7 == range -> XCD affinity. int4-vectorized.
//   5) agg_k    : one wave per dst node, 128-thr blocks; 16 lanes/edge (8 ch
//                 each), 8 edges/iter in two 4-edge groups, both gathers +
//                 src loads issued up front; padded gather indices clamped
//                 to 0. att pre-scaled by log2(e) -> one v_exp_f32.

#define NEG_SLOPE 0.2f
#define EPS_F 1e-16f
#define NRANGE 8
#define NCHUNK 32
#define SORT_B 1024
#define MAX_RSZ 12512   // >= ceil(N/NRANGE); LDS = 50 KB (u32)

typedef __attribute__((ext_vector_type(8))) short bf16x8;
typedef __attribute__((ext_vector_type(4))) float f32x4;

static __device__ __forceinline__ unsigned f2bf(float f) {
    unsigned u = __float_as_uint(f);
    return (u + 0x7fffu + ((u >> 16) & 1u)) >> 16;   // RNE
}
static __device__ __forceinline__ float bf2f(unsigned h) {
    return __uint_as_float(h << 16);
}
static __device__ __forceinline__ float bflo(unsigned u) {
    return __uint_as_float(u << 16);                 // low bf16 of a u32 pair
}
static __device__ __forceinline__ float bfhi(unsigned u) {
    return __uint_as_float(u & 0xffff0000u);         // high bf16 of a u32 pair
}

// ------------- LDS-histogram pass + W transpose -------------
__global__ __launch_bounds__(SORT_B) void histW_k(const int* __restrict__ dst, int E, int N,
                                                  int rsz, int chunk_e,
                                                  unsigned short* __restrict__ g,
                                                  const float* __restrict__ Wl,
                                                  const float* __restrict__ Wr,
                                                  unsigned short* __restrict__ Wtl,
                                                  unsigned short* __restrict__ Wtr) {
    if (blockIdx.x == NRANGE * NCHUNK) {
        for (int mat = 0; mat < 2; ++mat) {
            const float* W = mat ? Wr : Wl;
            unsigned short* Wt = mat ? Wtr : Wtl;
            for (int i = 0; i < 16; ++i) {
                int idx = (int)threadIdx.x + i * SORT_B;
                int k = idx >> 7, n = idx & 127;
                Wt[n * 128 + k] = (unsigned short)f2bf(W[idx]);
            }
        }
        return;
    }
    __shared__ unsigned lcnt[MAX_RSZ];
    const int r = blockIdx.x & (NRANGE - 1);
    const int c = blockIdx.x >> 3;
    const unsigned r_lo = (unsigned)(r * rsz);
    const int e0 = c * chunk_e;
    const int e1 = min(e0 + chunk_e, E);

    for (int i = threadIdx.x; i < rsz; i += SORT_B) lcnt[i] = 0u;
    __syncthreads();

    int e_vec_end = e0;
    if ((((uintptr_t)(dst + e0)) & 15) == 0) {          // int4-aligned fast path
        const int nq = (e1 - e0) >> 2;
        const int4* dq = (const int4*)(dst + e0);
        for (int q = (int)threadIdx.x; q < nq; q += SORT_B) {
            int4 d4 = dq[q];
            unsigned dd;
            dd = (unsigned)d4.x - r_lo; if (dd < (unsigned)rsz) atomicAdd(&lcnt[dd], 1u);
            dd = (unsigned)d4.y - r_lo; if (dd < (unsigned)rsz) atomicAdd(&lcnt[dd], 1u);
            dd = (unsigned)d4.z - r_lo; if (dd < (unsigned)rsz) atomicAdd(&lcnt[dd], 1u);
            dd = (unsigned)d4.w - r_lo; if (dd < (unsigned)rsz) atomicAdd(&lcnt[dd], 1u);
        }
        e_vec_end = e0 + (nq << 2);
    }
    for (int e = e_vec_end + (int)threadIdx.x; e < e1; e += SORT_B) {
        unsigned dd = (unsigned)dst[e] - r_lo;
        if (dd < (unsigned)rsz) atomicAdd(&lcnt[dd], 1u);   // LDS atomic
    }
    __syncthreads();
    unsigned short* gc = g + (size_t)c * N + r_lo;
    int lim = min(rsz, N - (int)r_lo);
    for (int i = threadIdx.x; i < lim; i += SORT_B) gc[i] = (unsigned short)lcnt[i];
}

// ------------- MFMA GEMM: xl = x@Wl, xr = x@Wr (bf16 in, bf16 out) -------------
#define LROW 136
__global__ __launch_bounds__(256) void mfma_gemm_k(const float* __restrict__ A,
                                                   const unsigned short* __restrict__ Wtl,
                                                   const unsigned short* __restrict__ Wtr,
                                                   unsigned short* __restrict__ xl,
                                                   unsigned short* __restrict__ xr,
                                                   int nrows) {
    __shared__ unsigned short As[64 * LROW];
    __shared__ unsigned short Ws[128 * LROW];
    const int tid = threadIdx.x;
    const int wave = tid >> 6, lane = tid & 63;
    const int quad = lane >> 4, m16 = lane & 15;
    const int row0 = blockIdx.x * 64;

#pragma unroll
    for (int i = 0; i < 8; ++i) {
        int idx = tid + i * 256;
        int r = idx >> 5, c4 = idx & 31;
        int gr = row0 + r;
        gr = gr < nrows ? gr : nrows - 1;
        float4 v = *(const float4*)(A + (size_t)gr * 128 + c4 * 4);
        ushort4 b;
        b.x = (unsigned short)f2bf(v.x);
        b.y = (unsigned short)f2bf(v.y);
        b.z = (unsigned short)f2bf(v.z);
        b.w = (unsigned short)f2bf(v.w);
        *(ushort4*)(&As[r * LROW + c4 * 4]) = b;
    }
#pragma unroll
    for (int i = 0; i < 8; ++i) {
        int idx = tid + i * 256;
        int n = idx >> 4, kq = idx & 15;
        *(uint4*)(&Ws[n * LROW + kq * 8]) = *(const uint4*)(Wtl + n * 128 + kq * 8);
    }
    __syncthreads();

    bf16x8 af[4];
#pragma unroll
    for (int ks = 0; ks < 4; ++ks)
        af[ks] = *(const bf16x8*)(&As[(wave * 16 + m16) * LROW + ks * 32 + quad * 8]);

    f32x4 acc[8];
#pragma unroll
    for (int ct = 0; ct < 8; ++ct) acc[ct] = (f32x4){0.f, 0.f, 0.f, 0.f};
#pragma unroll
    for (int ct = 0; ct < 8; ++ct)
#pragma unroll
        for (int ks = 0; ks < 4; ++ks) {
            bf16x8 bf = *(const bf16x8*)(&Ws[(ct * 16 + m16) * LROW + ks * 32 + quad * 8]);
            acc[ct] = __builtin_amdgcn_mfma_f32_16x16x32_bf16(af[ks], bf, acc[ct], 0, 0, 0);
        }
#pragma unroll
    for (int ct = 0; ct < 8; ++ct)
#pragma unroll
        for (int r = 0; r < 4; ++r) {
            int grow = row0 + wave * 16 + quad * 4 + r;
            if (grow < nrows) xl[(size_t)grow * 128 + ct * 16 + m16] = (unsigned short)f2bf(acc[ct][r]);
        }

    __syncthreads();
#pragma unroll
    for (int i = 0; i < 8; ++i) {
        int idx = tid + i * 256;
        int n = idx >> 4, kq = idx & 15;
        *(uint4*)(&Ws[n * LROW + kq * 8]) = *(const uint4*)(Wtr + n * 128 + kq * 8);
    }
    __syncthreads();

#pragma unroll
    for (int ct = 0; ct < 8; ++ct) acc[ct] = (f32x4){0.f, 0.f, 0.f, 0.f};
#pragma unroll
    for (int ct = 0; ct < 8; ++ct)
#pragma unroll
        for (int ks = 0; ks < 4; ++ks) {
            bf16x8 bf = *(const bf16x8*)(&Ws[(ct * 16 + m16) * LROW + ks * 32 + quad * 8]);
            acc[ct] = __builtin_amdgcn_mfma_f32_16x16x32_bf16(af[ks], bf, acc[ct], 0, 0, 0);
        }
#pragma unroll
    for (int ct = 0; ct < 8; ++ct)
#pragma unroll
        for (int r = 0; r < 4; ++r) {
            int grow = row0 + wave * 16 + quad * 4 + r;
            if (grow < nrows) xr[(size_t)grow * 128 + ct * 16 + m16] = (unsigned short)f2bf(acc[ct][r]);
        }
}

// ---------------- scanA: fused column-sum of g + per-block exclusive scan ----------------
#define SCAN_B 256
__global__ __launch_bounds__(SCAN_B) void scanA_k(const unsigned short* __restrict__ g, int n,
                                                  int* __restrict__ row_start,
                                                  int* __restrict__ bsum) {
    const int tid = threadIdx.x, lane = tid & 63, wid = tid >> 6;
    const int d = blockIdx.x * SCAN_B + tid;
    int v = 0;
    if (d < n) {
        unsigned s = 0;
#pragma unroll
        for (int c = 0; c < NCHUNK; ++c) s += g[(size_t)c * n + d];
        v = (int)s;
    }
    int inc = v;
#pragma unroll
    for (int dd = 1; dd < 64; dd <<= 1) {
        int t = __shfl_up(inc, dd);
        if (lane >= dd) inc += t;
    }
    __shared__ int wsum[SCAN_B / 64];
    if (lane == 63) wsum[wid] = inc;
    __syncthreads();
    int add = 0;
    for (int w = 0; w < wid; ++w) add += wsum[w];
    inc += add;
    if (d < n) row_start[d] = inc - v;
    if (tid == SCAN_B - 1) bsum[blockIdx.x] = inc;
}

// ------------- merged scanB + scanC + cbase: each block reduces its own prefix -------------
// bsum[] holds per-block inclusive totals from scanA; block b's offset is
// sum(bsum[0..b)) — <=391 L2-hot ints, reduced by 256 threads.
__global__ __launch_bounds__(SCAN_B) void scanCb_k(int* __restrict__ row_start,
                                                   const int* __restrict__ bsum,
                                                   const unsigned short* __restrict__ g,
                                                   int N, int E,
                                                   int* __restrict__ src_sorted,
                                                   unsigned* __restrict__ base) {
    const int tid = threadIdx.x;
    const int lane = tid & 63, wid = tid >> 6;
    // ---- block-prefix reduction (ALL threads; no early return before barrier) ----
    int partial = 0;
    for (int w = tid; w < (int)blockIdx.x; w += SCAN_B) partial += bsum[w];
#pragma unroll
    for (int dd = 1; dd < 64; dd <<= 1) partial += __shfl_xor(partial, dd);
    __shared__ int wred[SCAN_B / 64];
    if (lane == 0) wred[wid] = partial;
    __syncthreads();
    int add = 0;
#pragma unroll
    for (int w = 0; w < SCAN_B / 64; ++w) add += wred[w];

    const int d = blockIdx.x * SCAN_B + tid;
    if (blockIdx.x == 0 && tid == 0) row_start[N] = E;
    if (blockIdx.x == 0 && tid < 16) src_sorted[E + tid] = 0;
    if (d >= N) return;
    unsigned run = (unsigned)(row_start[d] + add);
    row_start[d] = (int)run;
#pragma unroll
    for (int c = 0; c < NCHUNK; ++c) {
        base[(size_t)c * N + d] = run;
        run += g[(size_t)c * N + d];
    }
}

// ------------- scatter via LDS cursors (no global atomics) -------------
__global__ __launch_bounds__(SORT_B) void scat_k(const int* __restrict__ src,
                                                 const int* __restrict__ dst, int E, int N,
                                                 int rsz, int chunk_e,
                                                 const unsigned* __restrict__ base,
                                                 int* __restrict__ src_sorted) {
    __shared__ unsigned lcur[MAX_RSZ];
    const int r = blockIdx.x & (NRANGE - 1);
    const int c = blockIdx.x >> 3;
    const unsigned r_lo = (unsigned)(r * rsz);
    const int e0 = c * chunk_e;
    const int e1 = min(e0 + chunk_e, E);

    const unsigned* bc = base + (size_t)c * N + r_lo;
    int lim = min(rsz, N - (int)r_lo);
    for (int i = threadIdx.x; i < lim; i += SORT_B) lcur[i] = bc[i];
    __syncthreads();

    int e_vec_end = e0;
    if (((((uintptr_t)(dst + e0)) | ((uintptr_t)(src + e0))) & 15) == 0) {
        const int nq = (e1 - e0) >> 2;
        const int4* dq = (const int4*)(dst + e0);
        const int4* sq = (const int4*)(src + e0);
        for (int q = (int)threadIdx.x; q < nq; q += SORT_B) {
            int4 d4 = dq[q];
            int4 s4 = sq[q];
            unsigned dd;
            dd = (unsigned)d4.x - r_lo;
            if (dd < (unsigned)rsz) { unsigned pos = atomicAdd(&lcur[dd], 1u); src_sorted[pos] = s4.x << 8; }
            dd = (unsigned)d4.y - r_lo;
            if (dd < (unsigned)rsz) { unsigned pos = atomicAdd(&lcur[dd], 1u); src_sorted[pos] = s4.y << 8; }
            dd = (unsigned)d4.z - r_lo;
            if (dd < (unsigned)rsz) { unsigned pos = atomicAdd(&lcur[dd], 1u); src_sorted[pos] = s4.z << 8; }
            dd = (unsigned)d4.w - r_lo;
            if (dd < (unsigned)rsz) { unsigned pos = atomicAdd(&lcur[dd], 1u); src_sorted[pos] = s4.w << 8; }
        }
        e_vec_end = e0 + (nq << 2);
    }
    for (int e = e_vec_end + (int)threadIdx.x; e < e1; e += SORT_B) {
        unsigned dd = (unsigned)dst[e] - r_lo;
        if (dd < (unsigned)rsz) {
            unsigned pos = atomicAdd(&lcur[dd], 1u);   // LDS atomic
            src_sorted[pos] = src[e] << 8;             // byte offset of xl row
        }
    }
}

// ---------------- aggregation: one wave per dst node, 128-thread blocks ----------------
// 2 waves/block halves the workgroup-retirement imbalance granularity (r13:
// 64% occupancy with no static limiter = slot-holding by finished waves).
// 16 lanes per edge (8 channels each); 8 edges per iteration in two 4-edge
// groups (A: k+eg, B: k+4+eg). Both src loads and both uint4 gathers are
// issued before any compute -> 2 gathers + 2 src loads in flight per lane.
// Padded edge indices (>= k1) are CLAMPED to 0 so dead gathers hit the
// L1-resident row 0; their contributions die via the w=0 predicate.
// att pre-scaled by log2(e): exp(e) == exp2(log2e*e) == one v_exp_f32.
__global__ __launch_bounds__(128) void agg_k(const unsigned* __restrict__ xlb,
                                             const unsigned* __restrict__ xrb,
                                             const float* __restrict__ att,
                                             const float* __restrict__ bias,
                                             const int* __restrict__ row_start,
                                             const int* __restrict__ src_sorted,
                                             int n, float* __restrict__ out) {
    const int wave = threadIdx.x >> 6;
    const int lane = threadIdx.x & 63;
    const int i = blockIdx.x * 2 + wave;
    if (i >= n) return;

    const int sub = lane & 15;
    const int eg  = lane >> 4;
    const int cb  = sub * 16;               // byte offset within a 256 B row
    const char* xb = (const char*)xlb;

    uint4 xrv = *(const uint4*)(xrb + (size_t)i * 64 + sub * 4);
    const float xr0 = bflo(xrv.x), xr1 = bfhi(xrv.x);
    const float xr2 = bflo(xrv.y), xr3 = bfhi(xrv.y);
    const float xr4 = bflo(xrv.z), xr5 = bfhi(xrv.z);
    const float xr6 = bflo(xrv.w), xr7 = bfhi(xrv.w);

    const float L2E = 1.44269504088896f;
    float4 atA = *(const float4*)(att + sub * 8);
    float4 atB = *(const float4*)(att + sub * 8 + 4);
    atA.x *= L2E; atA.y *= L2E; atA.z *= L2E; atA.w *= L2E;
    atB.x *= L2E; atB.y *= L2E; atB.z *= L2E; atB.w *= L2E;

    const int k0 = row_start[i];
    const int k1 = row_start[i + 1];

    float l = 0.f;
    float A0 = 0.f, A1 = 0.f, A2 = 0.f, A3 = 0.f;
    float A4 = 0.f, A5 = 0.f, A6 = 0.f, A7 = 0.f;

    for (int k = k0; k < k1; k += 8) {
        // ---- issue all memory ops first (MLP); clamp dead gathers to row 0 ----
        int sA = src_sorted[k + eg];
        int sB = src_sorted[k + 4 + eg];
        sA = (k + eg < k1) ? sA : 0;
        sB = (k + 4 + eg < k1) ? sB : 0;
        uint4 vA = *(const uint4*)(xb + (unsigned)sA + cb);
        uint4 vB = *(const uint4*)(xb + (unsigned)sB + cb);

        // ---- group A ----
        {
            float x0 = bflo(vA.x), x1 = bfhi(vA.x);
            float x2 = bflo(vA.y), x3 = bfhi(vA.y);
            float x4 = bflo(vA.z), x5 = bfhi(vA.z);
            float x6 = bflo(vA.w), x7 = bfhi(vA.w);
            float h0 = x0 + xr0, h1 = x1 + xr1, h2 = x2 + xr2, h3 = x3 + xr3;
            float h4 = x4 + xr4, h5 = x5 + xr5, h6 = x6 + xr6, h7 = x7 + xr7;
            float t, p;
            t = fmaxf(h0, NEG_SLOPE * h0); p = atA.x * t;
            t = fmaxf(h1, NEG_SLOPE * h1); p = fmaf(atA.y, t, p);
            t = fmaxf(h2, NEG_SLOPE * h2); p = fmaf(atA.z, t, p);
            t = fmaxf(h3, NEG_SLOPE * h3); p = fmaf(atA.w, t, p);
            t = fmaxf(h4, NEG_SLOPE * h4); p = fmaf(atB.x, t, p);
            t = fmaxf(h5, NEG_SLOPE * h5); p = fmaf(atB.y, t, p);
            t = fmaxf(h6, NEG_SLOPE * h6); p = fmaf(atB.z, t, p);
            t = fmaxf(h7, NEG_SLOPE * h7); p = fmaf(atB.w, t, p);
            p += __shfl_xor(p, 1);
            p += __shfl_xor(p, 2);           // p = e[head], replicated in 4 lanes
            float w;
            asm("v_exp_f32 %0, %1" : "=v"(w) : "v"(p));   // 2^p == exp(e)
            w = (k + eg < k1) ? w : 0.f;
            l += w;
            A0 = fmaf(w, x0, A0); A1 = fmaf(w, x1, A1);
            A2 = fmaf(w, x2, A2); A3 = fmaf(w, x3, A3);
            A4 = fmaf(w, x4, A4); A5 = fmaf(w, x5, A5);
            A6 = fmaf(w, x6, A6); A7 = fmaf(w, x7, A7);
        }
        // ---- group B ----
        {
            float x0 = bflo(vB.x), x1 = bfhi(vB.x);
            float x2 = bflo(vB.y), x3 = bfhi(vB.y);
            float x4 = bflo(vB.z), x5 = bfhi(vB.z);
            float x6 = bflo(vB.w), x7 = bfhi(vB.w);
            float h0 = x0 + xr0, h1 = x1 + xr1, h2 = x2 + xr2, h3 = x3 + xr3;
            float h4 = x4 + xr4, h5 = x5 + xr5, h6 = x6 + xr6, h7 = x7 + xr7;
            float t, p;
            t = fmaxf(h0, NEG_SLOPE * h0); p = atA.x * t;
            t = fmaxf(h1, NEG_SLOPE * h1); p = fmaf(atA.y, t, p);
            t = fmaxf(h2, NEG_SLOPE * h2); p = fmaf(atA.z, t, p);
            t = fmaxf(h3, NEG_SLOPE * h3); p = fmaf(atA.w, t, p);
            t = fmaxf(h4, NEG_SLOPE * h4); p = fmaf(atB.x, t, p);
            t = fmaxf(h5, NEG_SLOPE * h5); p = fmaf(atB.y, t, p);
            t = fmaxf(h6, NEG_SLOPE * h6); p = fmaf(atB.z, t, p);
            t = fmaxf(h7, NEG_SLOPE * h7); p = fmaf(atB.w, t, p);
            p += __shfl_xor(p, 1);
            p += __shfl_xor(p, 2);
            float w;
            asm("v_exp_f32 %0, %1" : "=v"(w) : "v"(p));
            w = (k + 4 + eg < k1) ? w : 0.f;
            l += w;
            A0 = fmaf(w, x0, A0); A1 = fmaf(w, x1, A1);
            A2 = fmaf(w, x2, A2); A3 = fmaf(w, x3, A3);
            A4 = fmaf(w, x4, A4); A5 = fmaf(w, x5, A5);
            A6 = fmaf(w, x6, A6); A7 = fmaf(w, x7, A7);
        }
    }

    l  += __shfl_xor(l, 16);  l  += __shfl_xor(l, 32);
    A0 += __shfl_xor(A0, 16); A0 += __shfl_xor(A0, 32);
    A1 += __shfl_xor(A1, 16); A1 += __shfl_xor(A1, 32);
    A2 += __shfl_xor(A2, 16); A2 += __shfl_xor(A2, 32);
    A3 += __shfl_xor(A3, 16); A3 += __shfl_xor(A3, 32);
    A4 += __shfl_xor(A4, 16); A4 += __shfl_xor(A4, 32);
    A5 += __shfl_xor(A5, 16); A5 += __shfl_xor(A5, 32);
    A6 += __shfl_xor(A6, 16); A6 += __shfl_xor(A6, 32);
    A7 += __shfl_xor(A7, 16); A7 += __shfl_xor(A7, 32);

    if (eg == 0) {
        float inv = 1.f / (l + EPS_F);
        float4 b0 = *(const float4*)(bias + sub * 8);
        float4 b1 = *(const float4*)(bias + sub * 8 + 4);
        float4 o0 = {fmaf(A0, inv, b0.x), fmaf(A1, inv, b0.y),
                     fmaf(A2, inv, b0.z), fmaf(A3, inv, b0.w)};
        float4 o1 = {fmaf(A4, inv, b1.x), fmaf(A5, inv, b1.y),
                     fmaf(A6, inv, b1.z), fmaf(A7, inv, b1.w)};
        *(float4*)(out + (size_t)i * 128 + sub * 8)     = o0;
        *(float4*)(out + (size_t)i * 128 + sub * 8 + 4) = o1;
    }
}

// ---------------- launch ----------------
extern "C" void kernel_launch(void* const* d_in, const int* in_sizes, int n_in,
                              void* d_out, int out_size, void* d_ws, size_t ws_size,
                              hipStream_t stream) {
    const float* x    = (const float*)d_in[0];
    const int*   ei   = (const int*)d_in[1];
    const float* W_l  = (const float*)d_in[2];
    const float* W_r  = (const float*)d_in[3];
    const float* att  = (const float*)d_in[4];
    const float* bias = (const float*)d_in[5];
    float* out = (float*)d_out;

    const int N = in_sizes[0] / 128;
    const int E = in_sizes[1] / 2;
    const int* src = ei;
    const int* dst = ei + E;

    char* ws = (char*)d_ws;
    size_t off = 0;
    auto alloc = [&](size_t bytes) {
        void* p = ws + off;
        off += (bytes + 15) & ~(size_t)15;
        return p;
    };
    unsigned* xlb       = (unsigned*)alloc((size_t)N * 64 * 4);        // bf16 [N][128]
    unsigned* xrb       = (unsigned*)alloc((size_t)N * 64 * 4);
    unsigned short* g   = (unsigned short*)alloc((size_t)NCHUNK * N * 2);  // 6.4 MB
    unsigned* base      = (unsigned*)alloc((size_t)NCHUNK * N * 4);        // 12.8 MB
    int* row_start      = (int*)alloc((size_t)(N + 1) * 4);
    const int nsb = (N + SCAN_B - 1) / SCAN_B;
    int* bsum           = (int*)alloc((size_t)nsb * 4);
    int* src_sorted     = (int*)alloc((size_t)(E + 16) * 4);
    unsigned short* Wtl = (unsigned short*)alloc((size_t)128 * 128 * 2);
    unsigned short* Wtr = (unsigned short*)alloc((size_t)128 * 128 * 2);
    (void)ws_size;

    const int rsz = (N + NRANGE - 1) / NRANGE;              // 12500 (<= MAX_RSZ)
    int chunk_e = (E + NCHUNK - 1) / NCHUNK;                // 50000 (< 65536: u16 safe)
    chunk_e = (chunk_e + 3) & ~3;                           // 16B-align chunk starts

    histW_k<<<NRANGE * NCHUNK + 1, SORT_B, 0, stream>>>(dst, E, N, rsz, chunk_e, g,
                                                        W_l, W_r, Wtl, Wtr);

    const int gB = (N + 63) / 64;
    mfma_gemm_k<<<gB, 256, 0, stream>>>(x, Wtl, Wtr,
                                        (unsigned short*)xlb, (unsigned short*)xrb, N);

    scanA_k<<<nsb, SCAN_B, 0, stream>>>(g, N, row_start, bsum);
    scanCb_k<<<nsb, SCAN_B, 0, stream>>>(row_start, bsum, g, N, E, src_sorted, base);

    scat_k<<<NRANGE * NCHUNK, SORT_B, 0, stream>>>(src, dst, E, N, rsz, chunk_e,
                                                   base, src_sorted);

    agg_k<<<(N + 1) / 2, 128, 0, stream>>>(xlb, xrb, att, bias, row_start, src_sorted, N, out);
}